// Round 11
// baseline (105.265 us; speedup 1.0000x reference)
//
#include <hip/hip_runtime.h>
#include <hip/hip_bf16.h>

#define IN_F 256
#define OU_F 64
#define BKN 128          // nodes per bucket
#define BSHIFT 7
#define NBMAX 512        // max buckets supported
#define PCHUNK 2048      // edges per partition block
#define STAGE_CAP 4096   // max records staged in LDS by csr_kernel
#define NHIST 64         // histogram-role blocks in fused kernel

typedef __attribute__((ext_vector_type(8))) short short8;
typedef __attribute__((ext_vector_type(4))) float f32x4;

__device__ inline short8 cvt8(float4 a, float4 b)
{
    union { short8 s8; __hip_bfloat162 h2[4]; } u;
    u.h2[0] = __float22bfloat162_rn(make_float2(a.x, a.y));
    u.h2[1] = __float22bfloat162_rn(make_float2(a.z, a.w));
    u.h2[2] = __float22bfloat162_rn(make_float2(b.x, b.y));
    u.h2[3] = __float22bfloat162_rn(make_float2(b.z, b.w));
    return u.s8;
}

// ---------------- fused: gemm (2 tiles/block) + hist+scan (ticket, no spin) ----------------
// Blocks [0, NHIST): histogram col into LDS, add to global bcnt, ticket;
// last block scans -> boffs/bcursor, then exits (no spin -> order-safe).
// Blocks [NHIST, NHIST+ntiles2): 128 rows each (2x 64-row tiles), W staged
// once to LDS then held in 16 register B-frags; inner loop has no LDS/barrier.
__global__ void __launch_bounds__(512, 4)
fused_gemm_hist(const float* __restrict__ h, const float* __restrict__ W,
                __hip_bfloat16* __restrict__ hp, const int* __restrict__ col,
                int* __restrict__ bcnt, int* __restrict__ boffs,
                int* __restrict__ bcursor, int N, int E, int NB)
{
    union Sh {
        unsigned short Wt[64][264];               // gemm: 33792 B
        struct { int lh[NBMAX]; int s[256]; } hh; // hist: 3072 B
    };
    __shared__ Sh sh;
    __shared__ int isLast;
    const int t   = threadIdx.x;
    const int bid = blockIdx.x;

    if (bid < NHIST) {
        // ---- histogram role ----
        for (int i = t; i < NBMAX; i += 512) sh.hh.lh[i] = 0;
        __syncthreads();
        const int n4 = E >> 2;
        const int4* c4 = (const int4*)col;
        for (int i = bid * 512 + t; i < n4; i += NHIST * 512) {
            int4 v = c4[i];
            atomicAdd(&sh.hh.lh[v.x >> BSHIFT], 1);
            atomicAdd(&sh.hh.lh[v.y >> BSHIFT], 1);
            atomicAdd(&sh.hh.lh[v.z >> BSHIFT], 1);
            atomicAdd(&sh.hh.lh[v.w >> BSHIFT], 1);
        }
        if (bid == 0)
            for (int e = (n4 << 2) + t; e < E; e += 512)
                atomicAdd(&sh.hh.lh[col[e] >> BSHIFT], 1);
        __syncthreads();
        for (int i = t; i < NB; i += 512)
            if (sh.hh.lh[i]) atomicAdd(&bcnt[i], sh.hh.lh[i]);
        __threadfence();
        __syncthreads();
        if (t == 0) {
            int v = atomicAdd(&bcnt[NBMAX], 1);
            isLast = (v == NHIST - 1);
        }
        __syncthreads();
        if (!isLast) return;

        // last hist block: exclusive scan of global counts
        for (int i = t; i < NB; i += 512)
            sh.hh.lh[i] = __hip_atomic_load(&bcnt[i], __ATOMIC_RELAXED,
                                            __HIP_MEMORY_SCOPE_AGENT);
        // lh[NB..NBMAX) are still 0 (cols < N never touch them)
        __syncthreads();
        int s0 = 0, s1 = 0;
        if (t < 256) {
            s0 = sh.hh.lh[2 * t];
            s1 = s0 + sh.hh.lh[2 * t + 1];
            sh.hh.s[t] = s1;
        }
        __syncthreads();
        for (int d = 1; d < 256; d <<= 1) {
            int v = (t < 256 && t >= d) ? sh.hh.s[t - d] : 0;
            __syncthreads();
            if (t < 256) sh.hh.s[t] += v;
            __syncthreads();
        }
        if (t < 256) {
            int excl = t ? sh.hh.s[t - 1] : 0;
            int i0 = 2 * t, i1 = 2 * t + 1;
            if (i0 < NB) { boffs[i0] = excl;      bcursor[i0] = excl;      }
            if (i1 < NB) { boffs[i1] = excl + s0; bcursor[i1] = excl + s0; }
            if (t == 255) boffs[NB] = sh.hh.s[255];
        }
        return;
    }

    // ---- gemm role ----
    const int tb = bid - NHIST;
#pragma unroll
    for (int i = 0; i < 16; ++i) {
        int p  = t + i * 512;          // 8192 (col, k-pair) slots
        int c  = p & 63;
        int k0 = (p >> 6) << 1;
        float x = W[(size_t)k0 * OU_F + c];
        float y = W[(size_t)(k0 + 1) * OU_F + c];
        __hip_bfloat162 bb = __float22bfloat162_rn(make_float2(x, y));
        *reinterpret_cast<unsigned*>(&sh.Wt[c][k0]) = *reinterpret_cast<unsigned*>(&bb);
    }
    __syncthreads();

    const int l   = t & 63;
    const int wv  = t >> 6;           // 0..7
    const int cl  = l & 15;
    const int kg  = l >> 4;           // 0..3
    const int rg4 = wv & 3;           // row group within 64-row tile
    const int cg  = wv >> 2;          // col group (32 cols each)

    short8 bfr[2][8];
#pragma unroll
    for (int nt2 = 0; nt2 < 2; ++nt2)
#pragma unroll
        for (int ks = 0; ks < 8; ++ks)
            bfr[nt2][ks] = *reinterpret_cast<const short8*>(
                &sh.Wt[cg * 32 + nt2 * 16 + cl][ks * 32 + kg * 8]);

#pragma unroll
    for (int tt = 0; tt < 2; ++tt) {
        const int rbase = tb * 128 + tt * 64 + rg4 * 16;
        const int r     = rbase + cl;
        const int rld   = min(r, N - 1);
        const float4* hrow = reinterpret_cast<const float4*>(h) + (size_t)rld * (IN_F / 4);

        f32x4 acc0 = (f32x4){0.f, 0.f, 0.f, 0.f};
        f32x4 acc1 = (f32x4){0.f, 0.f, 0.f, 0.f};
#pragma unroll
        for (int ks = 0; ks < 8; ++ks) {
            float4 a0 = hrow[ks * 8 + kg * 2];
            float4 a1 = hrow[ks * 8 + kg * 2 + 1];
            short8 af = cvt8(a0, a1);
            acc0 = __builtin_amdgcn_mfma_f32_16x16x32_bf16(af, bfr[0][ks], acc0, 0, 0, 0);
            acc1 = __builtin_amdgcn_mfma_f32_16x16x32_bf16(af, bfr[1][ks], acc1, 0, 0, 0);
        }
#pragma unroll
        for (int rg = 0; rg < 4; ++rg) {
            int rr = rbase + kg * 4 + rg;
            if (rr < N) {
                size_t base = (size_t)rr * OU_F + cg * 32 + cl;
                hp[base]      = __float2bfloat16(acc0[rg]);
                hp[base + 16] = __float2bfloat16(acc1[rg]);
            }
        }
    }
}

// ---------------- partition: counting-sort into buckets (2048/block, 23 KB LDS) ----------------
__global__ void __launch_bounds__(512, 4)
partition_kernel(const int* __restrict__ row, const int* __restrict__ col,
                 const float* __restrict__ vals, int* __restrict__ bcursor,
                 int2* __restrict__ epk, int E, int NB)
{
    __shared__ int  hist[NBMAX];
    __shared__ int  X[NBMAX];
    __shared__ int  gshift[NBMAX];
    __shared__ int  s[256];
    __shared__ int2 stage[PCHUNK];  // 16 KB

    const int t = threadIdx.x;
    const int base = blockIdx.x * PCHUNK;
    const int n = min(PCHUNK, E - base);

    for (int i = t; i < NBMAX; i += 512) hist[i] = 0;
    __syncthreads();

#pragma unroll
    for (int k = 0; k < PCHUNK / 512; ++k) {
        int i = t + k * 512;
        if (i < n) atomicAdd(&hist[col[base + i] >> BSHIFT], 1);
    }
    __syncthreads();

    int h0 = 0, h1 = 0;
    if (t < 256) {
        h0 = hist[2 * t];
        h1 = h0 + hist[2 * t + 1];
        s[t] = h1;
    }
    __syncthreads();
    for (int d = 1; d < 256; d <<= 1) {
        int v = (t < 256 && t >= d) ? s[t - d] : 0;
        __syncthreads();
        if (t < 256) s[t] += v;
        __syncthreads();
    }
    if (t < 256) {
        int excl = t ? s[t - 1] : 0;
        X[2 * t]     = excl;
        X[2 * t + 1] = excl + h0;
    }
    __syncthreads();

    for (int i = t; i < NB; i += 512) {
        int hc = hist[i];
        int g = hc ? atomicAdd(&bcursor[i], hc) : 0;
        gshift[i] = g - X[i];
    }
    __syncthreads();

#pragma unroll
    for (int k = 0; k < PCHUNK / 512; ++k) {
        int i = t + k * 512;
        if (i < n) {
            int e  = base + i;
            int cv = col[e];
            int b  = cv >> BSHIFT;
            int r  = atomicAdd(&X[b], 1);
            unsigned pk = (unsigned)row[e] | ((unsigned)(cv & (BKN - 1)) << 17);
            stage[r] = make_int2((int)pk, __float_as_int(vals[e]));
        }
    }
    __syncthreads();

    // copy-out: wave wv handles buckets wv, wv+8, ... (X[b] now = local end)
    const int l = t & 63, wv = t >> 6;
    for (int b = wv; b < NB; b += 8) {
        int cnt = hist[b];
        if (!cnt) continue;
        int src0 = X[b] - cnt;
        int dst0 = gshift[b] + src0;
        for (int j = l; j < cnt; j += 64)
            epk[dst0 + j] = stage[src0 + j];
    }
}

// ---------------- within-bucket counting sort by node + CSR offsets ----------------
__global__ void __launch_bounds__(512)
csr_kernel(const int2* __restrict__ epk, const int* __restrict__ boffs,
           int2* __restrict__ epk2, int* __restrict__ node_offs,
           int N, int NB)
{
    __shared__ int  cnt[BKN];
    __shared__ int  cur[BKN];
    __shared__ int2 stage[STAGE_CAP];   // 32 KB
    const int t = threadIdx.x;
    const int b = blockIdx.x;
    const int s = boffs[b], e = boffs[b + 1];
    const int n = e - s;
    const int node0 = b << BSHIFT;

    if (t < BKN) cnt[t] = 0;
    __syncthreads();
    for (int i = t; i < n; i += 512)
        atomicAdd(&cnt[((unsigned)epk[s + i].x) >> 17], 1);
    __syncthreads();

    if (t < 64) {
        int v0 = cnt[2 * t], v1 = cnt[2 * t + 1];
        int p = v0 + v1, sum = p;
#pragma unroll
        for (int d = 1; d < 64; d <<= 1) {
            int u = __shfl_up(sum, d);
            if (t >= d) sum += u;
        }
        int excl = sum - p;
        cur[2 * t]     = excl;
        cur[2 * t + 1] = excl + v0;
        int nd0 = node0 + 2 * t;
        if (nd0 < N)     node_offs[nd0]     = s + excl;
        if (nd0 + 1 < N) node_offs[nd0 + 1] = s + excl + v0;
    }
    if (b == NB - 1 && t == 0) node_offs[N] = e;
    __syncthreads();

    if (n <= STAGE_CAP) {
        for (int i = t; i < n; i += 512) {
            int2 r = epk[s + i];
            int pos = atomicAdd(&cur[((unsigned)r.x) >> 17], 1);
            stage[pos] = r;
        }
        __syncthreads();
        for (int i = t; i < n; i += 512)
            epk2[s + i] = stage[i];           // fully coalesced
    } else {
        for (int i = t; i < n; i += 512) {
            int2 r = epk[s + i];
            int pos = atomicAdd(&cur[((unsigned)r.x) >> 17], 1);
            epk2[s + pos] = r;
        }
    }
}

// ---------------- gather: one wave per destination node, no atomics ----------------
__global__ void __launch_bounds__(256)
gather_kernel(const __hip_bfloat16* __restrict__ hp, const int* __restrict__ node_offs,
              const int2* __restrict__ epk2, float* __restrict__ out, int N)
{
    int wid  = (int)((blockIdx.x * 256u + threadIdx.x) >> 6);   // node id
    int lane = threadIdx.x & 63;                                 // feature id
    if (wid >= N) return;
    int s = node_offs[wid], e = node_offs[wid + 1];
    float acc = 0.f;
    for (int base = s; base < e; base += 64) {
        int n = min(64, e - base);
        int2 m = make_int2(0, 0);
        if (lane < n) m = epk2[base + lane];
        int j = 0;
        for (; j + 4 <= n; j += 4) {
            unsigned r0 = (unsigned)__shfl(m.x, j)     & 0x1FFFFu;
            unsigned r1 = (unsigned)__shfl(m.x, j + 1) & 0x1FFFFu;
            unsigned r2 = (unsigned)__shfl(m.x, j + 2) & 0x1FFFFu;
            unsigned r3 = (unsigned)__shfl(m.x, j + 3) & 0x1FFFFu;
            float v0 = __int_as_float(__shfl(m.y, j));
            float v1 = __int_as_float(__shfl(m.y, j + 1));
            float v2 = __int_as_float(__shfl(m.y, j + 2));
            float v3 = __int_as_float(__shfl(m.y, j + 3));
            float x0 = __bfloat162float(hp[((size_t)r0 << 6) + lane]);
            float x1 = __bfloat162float(hp[((size_t)r1 << 6) + lane]);
            float x2 = __bfloat162float(hp[((size_t)r2 << 6) + lane]);
            float x3 = __bfloat162float(hp[((size_t)r3 << 6) + lane]);
            acc = fmaf(v0, x0, acc);
            acc = fmaf(v1, x1, acc);
            acc = fmaf(v2, x2, acc);
            acc = fmaf(v3, x3, acc);
        }
        for (; j < n; ++j) {
            unsigned r = (unsigned)__shfl(m.x, j) & 0x1FFFFu;
            float    v = __int_as_float(__shfl(m.y, j));
            acc = fmaf(v, __bfloat162float(hp[((size_t)r << 6) + lane]), acc);
        }
    }
    out[(size_t)wid * OU_F + lane] = acc;
}

// ---------------- fallback (atomic scatter) ----------------
__global__ void __launch_bounds__(256)
scatter_kernel(const __hip_bfloat16* __restrict__ hp, const int* __restrict__ row,
               const int* __restrict__ col, const float* __restrict__ vals,
               float* __restrict__ out, int E)
{
    unsigned int gid = blockIdx.x * 256u + threadIdx.x;
    int e = (int)(gid >> 6);
    if (e >= E) return;
    int f = (int)(gid & 63u);
    int r = row[e], c = col[e];
    float m = vals[e] * __bfloat162float(hp[(size_t)r * OU_F + f]);
    __hip_atomic_fetch_add(&out[(size_t)c * OU_F + f], m,
                           __ATOMIC_RELAXED, __HIP_MEMORY_SCOPE_AGENT);
}

extern "C" void kernel_launch(void* const* d_in, const int* in_sizes, int n_in,
                              void* d_out, int out_size, void* d_ws, size_t ws_size,
                              hipStream_t stream)
{
    const float* h    = (const float*)d_in[0];
    const float* W    = (const float*)d_in[1];
    const int*   row  = (const int*)d_in[2];
    const int*   col  = (const int*)d_in[3];
    const float* vals = (const float*)d_in[4];
    float*       out  = (float*)d_out;

    const int N = in_sizes[0] / IN_F;
    const int E = in_sizes[2];
    const int NB = (N + BKN - 1) / BKN;

    char*  ws  = (char*)d_ws;
    size_t off = 0;
    auto alloc = [&](size_t bytes) -> char* {
        char* p = ws + off;
        off = (off + bytes + 255) & ~(size_t)255;
        return p;
    };
    __hip_bfloat16* hp = (__hip_bfloat16*)alloc((size_t)N * OU_F * 2);
    int*   bcnt      = (int*)  alloc((size_t)(NBMAX + 1) * 4);   // [NBMAX] = ticket
    int*   boffs     = (int*)  alloc((size_t)(NBMAX + 1) * 4);
    int*   bcursor   = (int*)  alloc((size_t)NBMAX * 4);
    int*   node_offs = (int*)  alloc((size_t)(N + 1) * 4);
    int2*  epk       = (int2*) alloc((size_t)E * 8);
    int2*  epk2      = (int2*) alloc((size_t)E * 8);
    const bool fits = (off <= ws_size) && (NB <= NBMAX) && (N < 131072);

    const int ntiles2 = (N + 127) / 128;

    if (fits) {
        hipMemsetAsync(bcnt, 0, (size_t)(NBMAX + 1) * 4, stream);
        fused_gemm_hist<<<NHIST + ntiles2, 512, 0, stream>>>(
            h, W, hp, col, bcnt, boffs, bcursor, N, E, NB);
        partition_kernel<<<(E + PCHUNK - 1) / PCHUNK, 512, 0, stream>>>(
            row, col, vals, bcursor, epk, E, NB);
        csr_kernel<<<NB, 512, 0, stream>>>(epk, boffs, epk2, node_offs, N, NB);
        gather_kernel<<<(N + 3) / 4, 256, 0, stream>>>(hp, node_offs, epk2, out, N);
    } else {
        hipMemsetAsync(bcnt, 0, (size_t)(NBMAX + 1) * 4, stream);
        fused_gemm_hist<<<NHIST + ntiles2, 512, 0, stream>>>(
            h, W, hp, col, bcnt, boffs, bcursor, N, E, NB);
        hipMemsetAsync(d_out, 0, (size_t)out_size * sizeof(float), stream);
        unsigned long long total = (unsigned long long)E * 64ull;
        unsigned int sgrid = (unsigned int)((total + 255ull) / 256ull);
        scatter_kernel<<<sgrid, 256, 0, stream>>>(hp, row, col, vals, out, E);
    }
}